// Round 8
// baseline (25.103 us; speedup 1.0000x reference)
//
#include <hip/hip_runtime.h>
#include <hip/hip_fp16.h>

#define GH 16
#define GW 16
#define GD 8
#define GC 12
#define H 1024
#define W 1024
#define NB 2

#define ROWS 4                    // rows per block (4-aligned: never straddles the
                                  // i-cell boundaries at i == 32 mod 64)
#define TPB 256                   // 4 px/thread -> one row per iteration

// Relaxed barrier (prologue only): LDS consistency without draining stores.
#define RELAX_BARRIER()                                        \
  do {                                                         \
    asm volatile("s_waitcnt lgkmcnt(0)" ::: "memory");         \
    __builtin_amdgcn_s_barrier();                              \
  } while (0)

// LDS: TWO raw gi-planes (no pre-lerp), fp16 k-PAIR records.
// gP[plane][gj][r][0..23]: halfs [0..11] = row gk=r ch 0..11,
// halfs [12..23] = row gk=r+1 ch 0..11, r in [0,6]. Record 48 B, 16B-aligned;
// record stride puts the 7 r-values in disjoint bank quads; gj stride 176
// halfs rotates banks across gj.
#define GPR 24
#define NPAIR (GD - 1)
#define GJS_H (NPAIR * GPR + 8)   // 176 halfs per gj
#define LDS_HALFS (GW * GJS_H)    // 2816 halfs = 5632 B per plane

typedef float f4 __attribute__((ext_vector_type(4)));

// One 48B pair record (rows r,r+1 of one gj, one plane) -> 6 half2 accums.
__device__ inline void accum_rec(const __half* __restrict__ buf, int off,
                                 __half2 b0, __half2 b1, __half2* __restrict__ acc) {
  union U { uint4 u; __half2 h[4]; };
  const uint4* p = reinterpret_cast<const uint4*>(buf + off);
  U qa, qb, qc;
  qa.u = p[0]; qb.u = p[1]; qc.u = p[2];
  acc[0] = __hfma2(b0, qa.h[0], acc[0]);
  acc[1] = __hfma2(b0, qa.h[1], acc[1]);
  acc[2] = __hfma2(b0, qa.h[2], acc[2]);
  acc[3] = __hfma2(b0, qa.h[3], acc[3]);
  acc[4] = __hfma2(b0, qb.h[0], acc[4]);
  acc[5] = __hfma2(b0, qb.h[1], acc[5]);
  acc[0] = __hfma2(b1, qb.h[2], acc[0]);
  acc[1] = __hfma2(b1, qb.h[3], acc[1]);
  acc[2] = __hfma2(b1, qc.h[0], acc[2]);
  acc[3] = __hfma2(b1, qc.h[1], acc[3]);
  acc[4] = __hfma2(b1, qc.h[2], acc[4]);
  acc[5] = __hfma2(b1, qc.h[3], acc[5]);
}

// Raw (unlerped) pair-record write of one float4 (4 gj values) into one plane.
__device__ inline void slab_write_raw(__half* __restrict__ buf, int gq, int ck,
                                      float4 v) {
  int gk = ck & 7;
  int c  = ck >> 3;
  float vals[4] = {v.x, v.y, v.z, v.w};
#pragma unroll
  for (int m = 0; m < 4; ++m) {
    __half hv = __float2half(vals[m]);
    int base = (gq * 4 + m) * GJS_H;
    if (gk < GD - 1) buf[base + gk * GPR + c] = hv;            // row-low of pair gk
    if (gk > 0)      buf[base + (gk - 1) * GPR + 12 + c] = hv; // row-high of pair gk-1
  }
}

__global__ __launch_bounds__(TPB, 4) void slice_stream_k(const float* __restrict__ grid,
                                                         const float* __restrict__ guide,
                                                         float* __restrict__ out) {
  __shared__ __half gP[2][LDS_HALFS];

  const int tid = threadIdx.x;
  const int r0  = blockIdx.x * ROWS;     // global row base (= b*1024 + i0)
  const int b   = r0 >> 10;              // ROWS | 1024: b uniform per block
  const int i0  = r0 & (H - 1);
  const int j0  = tid << 2;              // 4 px/thread (quad within one j-cell)

  const float* gb      = grid + (size_t)b * (GC * GD * GH * GW);
  const float* guide_b = guide + ((size_t)b << 20);

  // --- i-cell (uniform for the whole block, all ROWS rows) ---
  float fi0  = (i0 + 0.5f) * (1.0f / 64.0f) - 0.5f;
  float fif  = floorf(fi0);
  int   gi0  = (int)fif;
  int gi0c = gi0 < 0 ? 0 : gi0;
  int gi1c = (gi0 + 1 > GH - 1) ? GH - 1 : gi0 + 1;

  // --- j cell (constant per thread) ---
  float fj  = (j0 + 0.5f) * (1.0f / 64.0f) - 0.5f;
  float fjf = floorf(fj);
  int   gj0 = (int)fjf;
  float tj0 = fj - fjf;
  int gj0c = gj0 < 0 ? 0 : gj0;
  int gj1c = (gj0 + 1 > GW - 1) ? GW - 1 : gj0 + 1;
  const int rj0 = gj0c * GJS_H;
  const int rj1 = gj1c * GJS_H;

  // --- prologue: prefetch all guide rows, stage BOTH raw gi-planes once ---
  float4 g_row[ROWS];
#pragma unroll
  for (int r = 0; r < ROWS; ++r)
    g_row[r] = *reinterpret_cast<const float4*>(guide_b + ((i0 + r) << 10) + j0);

#pragma unroll
  for (int q = 0; q < 2; ++q) {
    int s = tid + q * TPB;                 // 384 (c,gk,gj-quad) slots
    if (s < GC * GD * (GW / 4)) {
      int gq = s & 3;
      int ck = s >> 2;
      const float* rowbase = gb + (ck << 8);   // (c*8+gk)*256
      float4 v0 = *reinterpret_cast<const float4*>(rowbase + gi0c * GW + gq * 4);
      float4 v1 = *reinterpret_cast<const float4*>(rowbase + gi1c * GW + gq * 4);
      slab_write_raw(gP[0], gq, ck, v0);
      slab_write_raw(gP[1], gq, ck, v1);
    }
  }
  RELAX_BARRIER();   // the ONLY barrier in the kernel

  // --- steady state: ROWS barrier-free {compute + store} iterations ---
#pragma unroll
  for (int r = 0; r < ROWS; ++r) {
    const int i = i0 + r;

    // per-row i-weights (scalar; planes fixed)
    float fi = (i + 0.5f) * (1.0f / 64.0f) - 0.5f;
    float ti = fi - fif;                   // in [0,1) within this cell
    float wi0 = 1.0f - ti, wi1 = ti;

    __half2 acc[4][6];
    const float gv[4] = {g_row[r].x, g_row[r].y, g_row[r].z, g_row[r].w};

#pragma unroll
    for (int p = 0; p < 4; ++p) {
      float tj  = tj0 + p * (1.0f / 64.0f);
      float wj0 = 1.0f - tj, wj1 = tj;

      // k weights: plain lerp (sqrt(tk^2+1e-8)==tk within 1e-4 on [0,1));
      // clamp folded into pair weights (pair rr covers rows rr, rr+1).
      float fk  = gv[p] * (float)GD - 0.5f;
      float fkf = floorf(fk);
      int   gk0 = (int)fkf;                // in [-1, 7]
      float tk  = fk - fkf;
      bool lo = gk0 < 0, hi = gk0 > GD - 2;
      int  rr = lo ? 0 : (hi ? GD - 2 : gk0);
      float a0 = lo ? 1.0f : (hi ? 0.0f : 1.0f - tk);
      float a1 = lo ? 0.0f : (hi ? 1.0f : tk);

      // 8 coefficients: plane x gj x pair-half
      __half2 c000 = __float2half2_rn(wi0 * wj0 * a0);
      __half2 c001 = __float2half2_rn(wi0 * wj0 * a1);
      __half2 c010 = __float2half2_rn(wi0 * wj1 * a0);
      __half2 c011 = __float2half2_rn(wi0 * wj1 * a1);
      __half2 c100 = __float2half2_rn(wi1 * wj0 * a0);
      __half2 c101 = __float2half2_rn(wi1 * wj0 * a1);
      __half2 c110 = __float2half2_rn(wi1 * wj1 * a0);
      __half2 c111 = __float2half2_rn(wi1 * wj1 * a1);

      __half2* ap = acc[p];
#pragma unroll
      for (int t = 0; t < 6; ++t) ap[t] = __float2half2_rn(0.0f);

      int off = rr * GPR;
      accum_rec(gP[0], rj0 + off, c000, c001, ap);
      accum_rec(gP[0], rj1 + off, c010, c011, ap);
      accum_rec(gP[1], rj0 + off, c100, c101, ap);
      accum_rec(gP[1], rj1 + off, c110, c111, ap);
    }

    // stores: out[b][c][i][j0..j0+3], float4 per channel
    float* ob = out + (((size_t)b * GC) << 20) + ((size_t)i << 10) + j0;
#pragma unroll
    for (int c2 = 0; c2 < 6; ++c2) {
      float2 f0 = __half22float2(acc[0][c2]);
      float2 f1 = __half22float2(acc[1][c2]);
      float2 f2 = __half22float2(acc[2][c2]);
      float2 f3 = __half22float2(acc[3][c2]);
      f4 vlo = {f0.x, f1.x, f2.x, f3.x};   // channel 2*c2
      f4 vhi = {f0.y, f1.y, f2.y, f3.y};   // channel 2*c2+1
      *reinterpret_cast<f4*>(ob + ((size_t)(2 * c2) << 20))     = vlo;
      *reinterpret_cast<f4*>(ob + ((size_t)(2 * c2 + 1) << 20)) = vhi;
    }
  }
}

extern "C" void kernel_launch(void* const* d_in, const int* in_sizes, int n_in,
                              void* d_out, int out_size, void* d_ws, size_t ws_size,
                              hipStream_t stream) {
  const float* grid  = (const float*)d_in[0];   // (2,12,8,16,16) fp32
  const float* guide = (const float*)d_in[1];   // (2,1,1024,1024) fp32
  float* out = (float*)d_out;                   // (2,12,1024,1024) fp32

  const int nblocks = NB * H / ROWS;            // 512 blocks = 2 per CU
  slice_stream_k<<<nblocks, TPB, 0, stream>>>(grid, guide, out);
}

// Round 9
// 24.029 us; speedup vs baseline: 1.0447x; 1.0447x over previous
//
#include <hip/hip_runtime.h>
#include <hip/hip_fp16.h>

#define GH 16
#define GW 16
#define GD 8
#define GC 12
#define H 1024
#define W 1024
#define NB 2

#define CPB 2                    // channels per block
#define NCG (GC / CPB)           // 6 channel-groups
#define RPB 16                   // rows per block (16 | 32: i-cell uniform per block)
#define TPB 256                  // 4 px/thread -> one full row per iteration

// Per-row LDS record table, double-buffered. Record (rr, gj) = 16 B:
//   halfs: (c0,k=rr,gj),(c0,rr+1,gj) | (c1,rr,gj),(c1,rr+1,gj) |
//          (c0,rr,gj+1c),(c0,rr+1,gj+1c) | (c1,rr,gj+1c),(c1,rr+1,gj+1c)
// i-lerp already folded (per row). One ds_read_b128 per pixel serves both
// channels, both k-rows, both gj. rr-stride 17 slots (272 B) -> the 7 rr
// values hit distinct bank quads.
#define NREC 112                 // 7 rr * 16 gj
#define SLOTS_RR 17              // uint4 slots per rr (16 + 1 pad)
#define SLAB_U4 (7 * SLOTS_RR)   // 119 uint4 = 1904 B per buffer

// Relaxed barrier: LDS consistency only (no vmcnt drain -> output stores keep
// flowing across row iterations).
#define RELAX_BARRIER()                                        \
  do {                                                         \
    asm volatile("s_waitcnt lgkmcnt(0)" ::: "memory");         \
    __builtin_amdgcn_s_barrier();                              \
  } while (0)

__device__ inline float2 h2f(unsigned u) {
  __half2 h; *reinterpret_cast<unsigned*>(&h) = u; return __half22float2(h);
}
__device__ inline unsigned f2h2(float a, float b) {
  __half2 h = __floats2half2_rn(a, b);
  return *reinterpret_cast<unsigned*>(&h);
}

__global__ __launch_bounds__(TPB, 3) void slice_cs_k(const float* __restrict__ grid,
                                                     const float* __restrict__ guide,
                                                     float* __restrict__ out) {
  __shared__ uint4 recs[2][SLAB_U4];

  const int tid = threadIdx.x;
  const int bid = blockIdx.x;
  // blockIdx = cg*128 + b*64 + chunk. Same-chunk copies differ by 64/128
  // (both = 0 mod 8) -> all 12 land on ONE XCD -> guide rows L2-shared.
  const int cg    = bid >> 7;          // 0..5
  const int b     = (bid >> 6) & 1;
  const int chunk = bid & 63;
  const int i0    = chunk << 4;        // 16-row chunk, i-cell uniform
  const int c0    = cg * CPB;
  const int j0    = tid << 2;          // 4 px/thread (quad within one j-cell)

  const float* gb      = grid + (size_t)b * (GC * GD * GH * GW);
  const float* guide_b = guide + ((size_t)b << 20);

  // --- i-cell (fixed for the block; boundaries at i == 32 mod 64) ---
  float fi0 = (i0 + 0.5f) * (1.0f / 64.0f) - 0.5f;
  float fif = floorf(fi0);
  int   gi0 = (int)fif;
  int gi0c = gi0 < 0 ? 0 : gi0;
  int gi1c = (gi0 + 1 > GH - 1) ? GH - 1 : gi0 + 1;

  // --- j cell per thread ---
  float fj  = (j0 + 0.5f) * (1.0f / 64.0f) - 0.5f;
  float fjf = floorf(fj);
  int   gj0 = (int)fjf;
  float tj0 = fj - fjf;
  const bool lo_j = gj0 < 0;           // gj0c==gj1c==0: fold into cj
  const int gj0c = lo_j ? 0 : gj0;

  // --- record threads: load the block's grid slice into registers (once) ---
  // idx = c2*4 + dk*2 + js ; value = plane-lerp base/delta for (c0+c2, rr+dk,
  // gj+js clamped).
  const bool isrec = tid < NREC;
  const int rr = tid >> 4;             // 0..6
  const int gj = tid & 15;             // 0..15
  float rbase[8], rdelta[8];
  if (isrec) {
    int gjc1 = gj + 1 > GW - 1 ? GW - 1 : gj + 1;
#pragma unroll
    for (int c2 = 0; c2 < 2; ++c2)
#pragma unroll
      for (int dk = 0; dk < 2; ++dk)
#pragma unroll
        for (int js = 0; js < 2; ++js) {
          int c = c0 + c2, k = rr + dk;
          int gjp = js ? gjc1 : gj;
          int bix = ((c * GD + k) << 8) + gjp;   // (c*8+k)*256 + gj
          float v0 = gb[bix + (gi0c << 4)];
          float v1 = gb[bix + (gi1c << 4)];
          int idx = (c2 << 2) + (dk << 1) + js;
          rbase[idx]  = v0;
          rdelta[idx] = v1 - v0;
        }
  }

  // --- rebuild: i-lerp + fp16 pack + one ds_write_b128 per record thread ---
  auto rebuild = [&](int bufsel, float ti) {
    if (isrec) {
      float v[8];
#pragma unroll
      for (int t = 0; t < 8; ++t) v[t] = fmaf(ti, rdelta[t], rbase[t]);
      uint4 rec;
      rec.x = f2h2(v[0], v[2]);   // c0, gj : rows rr, rr+1
      rec.y = f2h2(v[4], v[6]);   // c1, gj
      rec.z = f2h2(v[1], v[3]);   // c0, gj+1
      rec.w = f2h2(v[5], v[7]);   // c1, gj+1
      recs[bufsel][rr * SLOTS_RR + gj] = rec;
    }
  };

  // --- prologue: build row i0 records ---
  rebuild(0, fi0 - fif);
  RELAX_BARRIER();

  int cur = 0;
#pragma unroll 2
  for (int r = 0; r < RPB; ++r) {
    const int i = i0 + r;
    float4 g4 = *reinterpret_cast<const float4*>(guide_b + (i << 10) + j0);
    const float gv[4] = {g4.x, g4.y, g4.z, g4.w};

    float o0[4], o1[4];
#pragma unroll
    for (int p = 0; p < 4; ++p) {
      float tj  = tj0 + p * (1.0f / 64.0f);
      float cj1 = lo_j ? 0.0f : tj;
      float cj0 = 1.0f - cj1;

      // k weights: plain lerp (sqrt(tk^2+1e-8)==tk within 1e-4 on [0,1));
      // clamps folded (pair rrp covers rows rrp, rrp+1; right-j via record dup)
      float fk  = gv[p] * (float)GD - 0.5f;
      float fkf = floorf(fk);
      int   gk0 = (int)fkf;              // in [-1, 7]
      float tk  = fk - fkf;
      bool lo_k = gk0 < 0, hi_k = gk0 > GD - 2;
      int  rrp = lo_k ? 0 : (hi_k ? GD - 2 : gk0);
      float a1 = lo_k ? 0.0f : (hi_k ? 1.0f : tk);
      float a0 = 1.0f - a1;

      float w00 = cj0 * a0, w01 = cj0 * a1;
      float w10 = cj1 * a0, w11 = cj1 * a1;

      uint4 q = recs[cur][rrp * SLOTS_RR + gj0c];   // ONE b128 per pixel
      float2 pa = h2f(q.x);   // c0, gj0: rows rrp, rrp+1
      float2 pb = h2f(q.y);   // c1, gj0
      float2 pc = h2f(q.z);   // c0, gj1
      float2 pd = h2f(q.w);   // c1, gj1
      o0[p] = w00 * pa.x + w01 * pa.y + w10 * pc.x + w11 * pc.y;
      o1[p] = w00 * pb.x + w01 * pb.y + w10 * pd.x + w11 * pd.y;
    }

    // stores: 2 contiguous plane streams per block (fill-kernel shape)
    float* ob = out + ((size_t)(b * GC + c0) << 20) + ((size_t)i << 10) + j0;
    *reinterpret_cast<float4*>(ob) = make_float4(o0[0], o0[1], o0[2], o0[3]);
    *reinterpret_cast<float4*>(ob + ((size_t)1 << 20)) =
        make_float4(o1[0], o1[1], o1[2], o1[3]);

    // rebuild next row into the other buffer; one relaxed barrier per row
    if (r + 1 < RPB) {
      float ti = ((i + 1) + 0.5f) * (1.0f / 64.0f) - 0.5f - fif;
      rebuild(cur ^ 1, ti);
      RELAX_BARRIER();
      cur ^= 1;
    }
  }
}

extern "C" void kernel_launch(void* const* d_in, const int* in_sizes, int n_in,
                              void* d_out, int out_size, void* d_ws, size_t ws_size,
                              hipStream_t stream) {
  const float* grid  = (const float*)d_in[0];   // (2,12,8,16,16) fp32
  const float* guide = (const float*)d_in[1];   // (2,1,1024,1024) fp32
  float* out = (float*)d_out;                   // (2,12,1024,1024) fp32

  const int nblocks = NCG * NB * (H / RPB);     // 6*2*64 = 768 = 3 per CU
  slice_cs_k<<<nblocks, TPB, 0, stream>>>(grid, guide, out);
}